// Round 2
// baseline (267.749 us; speedup 1.0000x reference)
//
#include <hip/hip_runtime.h>
#include <stdint.h>

#define SS 4096
#define EE 256
// log2(e)/16  (logit scale 1/NORM_FACTOR folded into exp2 conversion)
#define C2 0.0901684400555602f

typedef __bf16 bf16x8 __attribute__((ext_vector_type(8)));
typedef float  f32x4  __attribute__((ext_vector_type(4)));

#if __has_builtin(__builtin_amdgcn_exp2f)
#define EXP2(x) __builtin_amdgcn_exp2f(x)
#else
#define EXP2(x) exp2f(x)
#endif
#if __has_builtin(__builtin_amdgcn_rcpf)
#define RCP(x) __builtin_amdgcn_rcpf(x)
#else
#define RCP(x) (1.0f / (x))
#endif

__device__ __forceinline__ uint16_t bf16_rn(float f) {
  uint32_t u = __float_as_uint(f);
  uint32_t r = (u + 0x7fffu + ((u >> 16) & 1u)) >> 16;
  return (uint16_t)r;
}
__device__ __forceinline__ float bf2f(uint16_t h) {
  return __uint_as_float(((uint32_t)h) << 16);
}

__device__ __forceinline__ f32x4 mfma16(bf16x8 a, bf16x8 b, f32x4 c) {
  return __builtin_amdgcn_mfma_f32_16x16x32_bf16(a, b, c, 0, 0, 0);
}

// Stage R rows x 512B global -> LDS via global_load_lds(16B), XOR-swizzled
// (chunk cc of row r lands at physical cc^(r&7)); paired with read_frag.
template<int R>
__device__ __forceinline__ void stage_tile(const uint16_t* gsrc, char* lds, int tid) {
  constexpr int NPER = (R * 32) / 256;
  const int wave = tid >> 6;
  #pragma unroll
  for (int c = 0; c < NPER; ++c) {
    int chunk = c * 256 + tid;
    int r = chunk >> 5;
    int ccl = (chunk & 31) ^ (r & 7);
    const char* gp = (const char*)gsrc + (r * 32 + ccl) * 16;
    char* lp = lds + (c * 256 + wave * 64) * 16;
    __builtin_amdgcn_global_load_lds(
        (const __attribute__((address_space(1))) uint32_t*)(uintptr_t)gp,
        (__attribute__((address_space(3))) uint32_t*)(uintptr_t)lp,
        16, 0, 0);
  }
}

__device__ __forceinline__ bf16x8 read_frag(const char* lds, int row, int cc) {
  int ccp = cc ^ (row & 7);
  return *(const bf16x8*)(lds + (row * 32 + ccp) * 16);
}

// ---------------- K0: prep = xcast (blocks 0..4095) + W transpose-cast ------
__global__ void prep_kernel(const float* __restrict__ x, uint16_t* __restrict__ xb,
                            const float* __restrict__ Wq, const float* __restrict__ Wk,
                            const float* __restrict__ Wv, uint16_t* __restrict__ wt) {
  __shared__ float t[64][65];
  const int bid = blockIdx.x, tid = threadIdx.x;
  if (bid < 4096) {
    int i = bid * 256 + tid;
    float4 f = ((const float4*)x)[i];
    ushort4 o;
    o.x = bf16_rn(f.x); o.y = bf16_rn(f.y); o.z = bf16_rn(f.z); o.w = bf16_rn(f.w);
    ((ushort4*)xb)[i] = o;
    return;
  }
  // W transpose: 48 blocks = 3 mats x 16 (4x4) tiles of 64x64
  const int tb = bid - 4096;
  const int mat = tb >> 4, tt = tb & 15;
  const int ib = (tt >> 2) * 64, ob = (tt & 3) * 64;
  const float* W = (mat == 0) ? Wq : (mat == 1) ? Wk : Wv;
  #pragma unroll
  for (int p = 0; p < 4; ++p) {
    int idx = p * 256 + tid;
    int r = idx >> 4, c4 = idx & 15;      // row i=ib+r, cols o=ob+c4*4..+3
    float4 f = *(const float4*)&W[(size_t)(ib + r) * 256 + ob + c4 * 4];
    t[r][c4 * 4 + 0] = f.x; t[r][c4 * 4 + 1] = f.y;
    t[r][c4 * 4 + 2] = f.z; t[r][c4 * 4 + 3] = f.w;
  }
  __syncthreads();
  #pragma unroll
  for (int p = 0; p < 4; ++p) {
    int idx = p * 256 + tid;
    int o = idx >> 4, i4 = idx & 15;
    ushort4 u;
    u.x = bf16_rn(t[i4 * 4 + 0][o]);
    u.y = bf16_rn(t[i4 * 4 + 1][o]);
    u.z = bf16_rn(t[i4 * 4 + 2][o]);
    u.w = bf16_rn(t[i4 * 4 + 3][o]);
    *(ushort4*)&wt[((size_t)mat * 256 + ob + o) * 256 + ib + i4 * 4] = u;
  }
}

// ---------------- K1: fused QKV projection GEMM ----------------
// WG = 256 rows x 192-col chunk; A (4 waves x 64 rows) in registers from
// global; W tiles (64 cols x 256 K = 32 KB) double-buffered in LDS.
// Per nc per wave: 32 ds_read_b128 feed 128 MFMAs -> MFMA-bound.
__global__ __launch_bounds__(256, 2) void qkv_kernel(
    const uint16_t* __restrict__ xb, const uint16_t* __restrict__ wt,
    const float* __restrict__ bq, const float* __restrict__ bk, const float* __restrict__ bv,
    uint16_t* __restrict__ qo, uint16_t* __restrict__ ko, uint16_t* __restrict__ vo) {
  __shared__ char wsm[2][32768];
  const int tid = threadIdx.x;
  const int lane = tid & 63, wave = tid >> 6, quad = lane >> 4, lr = lane & 15;
  const int m0 = (blockIdx.x >> 2) * 256;
  const int cchunk = blockIdx.x & 3;          // 4 chunks of 192 cols over [q|k|v]
  const uint16_t* ab = xb + (size_t)(m0 + wave * 64) * EE;
  bf16x8 a[4][8];
  #pragma unroll
  for (int ms = 0; ms < 4; ++ms)
    #pragma unroll
    for (int f = 0; f < 8; ++f)
      a[ms][f] = *(const bf16x8*)(ab + (size_t)(ms * 16 + lr) * EE + f * 32 + quad * 8);
  stage_tile<64>(wt + (size_t)(cchunk * 192) * 256, wsm[0], tid);
  for (int nc = 0; nc < 3; ++nc) {
    __syncthreads();
    if (nc < 2)
      stage_tile<64>(wt + (size_t)(cchunk * 192 + (nc + 1) * 64) * 256, wsm[(nc + 1) & 1], tid);
    const char* tile = wsm[nc & 1];
    #pragma unroll
    for (int nt = 0; nt < 4; ++nt) {
      const int eg0 = cchunk * 192 + nc * 64 + nt * 16;   // global col base
      const int mat = eg0 >> 8;
      const int e = (eg0 & 255) + lr;
      const float* bias = (mat == 0) ? bq : (mat == 1) ? bk : bv;
      uint16_t* outp = (mat == 0) ? qo : (mat == 1) ? ko : vo;
      bf16x8 bf[8];
      #pragma unroll
      for (int f = 0; f < 8; ++f) bf[f] = read_frag(tile, nt * 16 + lr, f * 4 + quad);
      f32x4 acc[4] = {};
      #pragma unroll
      for (int f = 0; f < 8; ++f)
        #pragma unroll
        for (int ms = 0; ms < 4; ++ms)
          acc[ms] = mfma16(a[ms][f], bf[f], acc[ms]);
      const float bsv = bias[e];
      #pragma unroll
      for (int ms = 0; ms < 4; ++ms)
        #pragma unroll
        for (int r = 0; r < 4; ++r) {
          int row = m0 + wave * 64 + ms * 16 + quad * 4 + r;
          outp[(size_t)row * EE + e] = bf16_rn(acc[ms][r] + bsv);
        }
    }
  }
}

// ---------------- K2: pass A  l[s] = sum_t exp(q_s.k_t/16) ----------------
// Barrier-free: A (64 q-rows/wave) in registers, B-frags (16 keys/iter)
// straight from global (L2-resident). No LDS, no __syncthreads.
__global__ __launch_bounds__(256, 2) void scores_l_kernel(
    const uint16_t* __restrict__ q, const uint16_t* __restrict__ k,
    float* __restrict__ lacc) {
  const int tid = threadIdx.x;
  const int lane = tid & 63, wave = tid >> 6, quad = lane >> 4, lr = lane & 15;
  const int idx = blockIdx.x;
  const int b = idx >> 7, rem = idx & 127, qblk = rem >> 3, kch = rem & 7;
  const uint16_t* qb = q + (size_t)(b * SS + qblk * 256 + wave * 64) * EE;
  const uint16_t* kb = k + (size_t)(b * SS + kch * 512) * EE;
  bf16x8 a[4][8];
  #pragma unroll
  for (int ms = 0; ms < 4; ++ms)
    #pragma unroll
    for (int f = 0; f < 8; ++f)
      a[ms][f] = *(const bf16x8*)(qb + (size_t)(ms * 16 + lr) * EE + f * 32 + quad * 8);
  float accl[16];
  #pragma unroll
  for (int i = 0; i < 16; ++i) accl[i] = 0.f;
  #pragma unroll 2
  for (int kt = 0; kt < 32; ++kt) {          // 16 keys per iter
    bf16x8 bf[8];
    #pragma unroll
    for (int f = 0; f < 8; ++f)
      bf[f] = *(const bf16x8*)(kb + (size_t)(kt * 16 + lr) * EE + f * 32 + quad * 8);
    f32x4 acc[4] = {};
    #pragma unroll
    for (int f = 0; f < 8; ++f)
      #pragma unroll
      for (int ms = 0; ms < 4; ++ms)
        acc[ms] = mfma16(a[ms][f], bf[f], acc[ms]);
    #pragma unroll
    for (int ms = 0; ms < 4; ++ms)
      #pragma unroll
      for (int r = 0; r < 4; ++r)
        accl[ms * 4 + r] += EXP2(acc[ms][r] * C2);
  }
  #pragma unroll
  for (int d = 1; d < 16; d <<= 1)
    #pragma unroll
    for (int i = 0; i < 16; ++i)
      accl[i] += __shfl_xor(accl[i], d, 64);
  if (lr == 0) {
    float* lp = lacc + b * SS + qblk * 256 + wave * 64;
    #pragma unroll
    for (int ms = 0; ms < 4; ++ms)
      #pragma unroll
      for (int r = 0; r < 4; ++r)
        atomicAdd(&lp[ms * 16 + quad * 4 + r], accl[ms * 4 + r]);
  }
}

// ---------------- K3: pass B  w[t] = sum_s exp(q_s.k_t/16) / l[s] ----------
// Mirror of K2 with roles swapped; 1/l via v_rcp folded in (no rcp kernel).
__global__ __launch_bounds__(256, 2) void scores_w_kernel(
    const uint16_t* __restrict__ q, const uint16_t* __restrict__ k,
    const float* __restrict__ lacc, float* __restrict__ wacc) {
  const int tid = threadIdx.x;
  const int lane = tid & 63, wave = tid >> 6, quad = lane >> 4, lr = lane & 15;
  const int idx = blockIdx.x;
  const int b = idx >> 7, rem = idx & 127, kblk = rem >> 3, sch = rem & 7;
  const uint16_t* kb = k + (size_t)(b * SS + kblk * 256 + wave * 64) * EE;
  const uint16_t* qb = q + (size_t)(b * SS + sch * 512) * EE;
  const float* rlb = lacc + b * SS + sch * 512;
  bf16x8 a[4][8];
  #pragma unroll
  for (int ms = 0; ms < 4; ++ms)
    #pragma unroll
    for (int f = 0; f < 8; ++f)
      a[ms][f] = *(const bf16x8*)(kb + (size_t)(ms * 16 + lr) * EE + f * 32 + quad * 8);
  float accw[16];
  #pragma unroll
  for (int i = 0; i < 16; ++i) accw[i] = 0.f;
  #pragma unroll 2
  for (int kt = 0; kt < 32; ++kt) {          // 16 queries per iter
    float rlv = RCP(rlb[kt * 16 + lr]);      // 1/l for col s = kt*16+lr
    bf16x8 bf[8];
    #pragma unroll
    for (int f = 0; f < 8; ++f)
      bf[f] = *(const bf16x8*)(qb + (size_t)(kt * 16 + lr) * EE + f * 32 + quad * 8);
    f32x4 acc[4] = {};
    #pragma unroll
    for (int f = 0; f < 8; ++f)
      #pragma unroll
      for (int ms = 0; ms < 4; ++ms)
        acc[ms] = mfma16(a[ms][f], bf[f], acc[ms]);
    #pragma unroll
    for (int ms = 0; ms < 4; ++ms)
      #pragma unroll
      for (int r = 0; r < 4; ++r)
        accw[ms * 4 + r] += EXP2(acc[ms][r] * C2) * rlv;
  }
  #pragma unroll
  for (int d = 1; d < 16; d <<= 1)
    #pragma unroll
    for (int i = 0; i < 16; ++i)
      accw[i] += __shfl_xor(accw[i], d, 64);
  if (lr == 0) {
    float* wp = wacc + b * SS + kblk * 256 + wave * 64;
    #pragma unroll
    for (int ms = 0; ms < 4; ++ms)
      #pragma unroll
      for (int r = 0; r < 4; ++r)
        atomicAdd(&wp[ms * 16 + quad * 4 + r], accw[ms * 4 + r]);
  }
}

// ---------------- K4: out[b,e] = (1/S) sum_t w[t] v[t,e] ----------------
__global__ void pool_kernel(const float* __restrict__ wsum, const uint16_t* __restrict__ v,
                            float* __restrict__ out) {
  const int b = blockIdx.x >> 6, tc = blockIdx.x & 63;   // 64 chunks of 64 rows
  const int tr = threadIdx.x >> 6, eg = threadIdx.x & 63;
  float acc[4] = {0.f, 0.f, 0.f, 0.f};
  const float* wp = wsum + b * SS + tc * 64;
  const uint16_t* vp = v + (size_t)(b * SS + tc * 64) * EE;
  for (int t = tr; t < 64; t += 4) {
    float wv = wp[t];
    ushort4 x4 = *(const ushort4*)(vp + (size_t)t * EE + eg * 4);
    acc[0] += wv * bf2f(x4.x);
    acc[1] += wv * bf2f(x4.y);
    acc[2] += wv * bf2f(x4.z);
    acc[3] += wv * bf2f(x4.w);
  }
  const float inv = 1.0f / 4096.0f;
  #pragma unroll
  for (int j = 0; j < 4; ++j)
    atomicAdd(&out[b * 256 + eg * 4 + j], acc[j] * inv);
}

// ---------------- launch ----------------
extern "C" void kernel_launch(void* const* d_in, const int* in_sizes, int n_in,
                              void* d_out, int out_size, void* d_ws, size_t ws_size,
                              hipStream_t stream) {
  const float* x  = (const float*)d_in[0];
  const float* Wq = (const float*)d_in[1];
  const float* bq = (const float*)d_in[2];
  const float* Wk = (const float*)d_in[3];
  const float* bk = (const float*)d_in[4];
  const float* Wv = (const float*)d_in[5];
  const float* bv = (const float*)d_in[6];

  char* ws = (char*)d_ws;
  uint16_t* xb   = (uint16_t*)(ws);              //  8 MB  x bf16
  uint16_t* qb   = (uint16_t*)(ws + 8388608);    //  8 MB  q bf16
  uint16_t* kb   = (uint16_t*)(ws + 16777216);   //  8 MB  k bf16
  uint16_t* vb   = (uint16_t*)(ws + 25165824);   //  8 MB  v bf16
  uint16_t* wt   = (uint16_t*)(ws + 33554432);   // 384 KB WT bf16 (q|k|v transposed)
  float* l_arr   = (float*)(ws + 33947648);      // 64 KB  row sums
  float* w_arr   = (float*)(ws + 34013184);      // 64 KB  col weights (adjacent to l)
  float* out     = (float*)d_out;

  hipMemsetAsync(l_arr, 0, 2 * 65536, stream);   // zeros l + w
  hipMemsetAsync(out, 0, 1024 * sizeof(float), stream);

  prep_kernel<<<4144, 256, 0, stream>>>(x, xb, Wq, Wk, Wv, wt);
  qkv_kernel<<<256, 256, 0, stream>>>(xb, wt, bq, bk, bv, qb, kb, vb);
  scores_l_kernel<<<512, 256, 0, stream>>>(qb, kb, l_arr);
  scores_w_kernel<<<512, 256, 0, stream>>>(qb, kb, l_arr, w_arr);
  pool_kernel<<<256, 256, 0, stream>>>(w_arr, vb, out);
}

// Round 3
// 243.888 us; speedup vs baseline: 1.0978x; 1.0978x over previous
//
#include <hip/hip_runtime.h>
#include <stdint.h>

#define SS 4096
#define EE 256
// log2(e)/16  (logit scale 1/NORM_FACTOR folded into exp2 conversion)
#define C2 0.0901684400555602f

typedef __bf16 bf16x8 __attribute__((ext_vector_type(8)));
typedef float  f32x4  __attribute__((ext_vector_type(4)));

#if __has_builtin(__builtin_amdgcn_exp2f)
#define EXP2(x) __builtin_amdgcn_exp2f(x)
#else
#define EXP2(x) exp2f(x)
#endif
#if __has_builtin(__builtin_amdgcn_rcpf)
#define RCP(x) __builtin_amdgcn_rcpf(x)
#else
#define RCP(x) (1.0f / (x))
#endif

__device__ __forceinline__ uint16_t bf16_rn(float f) {
  uint32_t u = __float_as_uint(f);
  uint32_t r = (u + 0x7fffu + ((u >> 16) & 1u)) >> 16;
  return (uint16_t)r;
}
__device__ __forceinline__ float bf2f(uint16_t h) {
  return __uint_as_float(((uint32_t)h) << 16);
}
__device__ __forceinline__ bf16x8 pack_bf8(float4 a, float4 b) {
  union { bf16x8 v; uint16_t u[8]; } r;
  r.u[0] = bf16_rn(a.x); r.u[1] = bf16_rn(a.y);
  r.u[2] = bf16_rn(a.z); r.u[3] = bf16_rn(a.w);
  r.u[4] = bf16_rn(b.x); r.u[5] = bf16_rn(b.y);
  r.u[6] = bf16_rn(b.z); r.u[7] = bf16_rn(b.w);
  return r.v;
}

__device__ __forceinline__ f32x4 mfma16(bf16x8 a, bf16x8 b, f32x4 c) {
  return __builtin_amdgcn_mfma_f32_16x16x32_bf16(a, b, c, 0, 0, 0);
}

// Stage R rows x 512B global -> LDS via global_load_lds(16B), XOR-swizzled
// (chunk cc of row r lands at physical cc^(r&7)); paired with read_frag.
// Register-free transport: data never touches VGPRs (key lesson from R2).
template<int R>
__device__ __forceinline__ void stage_tile(const uint16_t* gsrc, char* lds, int tid) {
  constexpr int NPER = (R * 32) / 256;
  const int wave = tid >> 6;
  #pragma unroll
  for (int c = 0; c < NPER; ++c) {
    int chunk = c * 256 + tid;
    int r = chunk >> 5;
    int ccl = (chunk & 31) ^ (r & 7);
    const char* gp = (const char*)gsrc + (r * 32 + ccl) * 16;
    char* lp = lds + (c * 256 + wave * 64) * 16;
    __builtin_amdgcn_global_load_lds(
        (const __attribute__((address_space(1))) uint32_t*)(uintptr_t)gp,
        (__attribute__((address_space(3))) uint32_t*)(uintptr_t)lp,
        16, 0, 0);
  }
}

__device__ __forceinline__ bf16x8 read_frag(const char* lds, int row, int cc) {
  int ccp = cc ^ (row & 7);
  return *(const bf16x8*)(lds + (row * 32 + ccp) * 16);
}

// ---------------- K0: W transpose-cast -> WT[out][in] bf16 ----------------
__global__ void wcast_kernel(const float* __restrict__ Wq, const float* __restrict__ Wk,
                             const float* __restrict__ Wv, uint16_t* __restrict__ wt) {
  __shared__ float t[64][65];
  const int tb = blockIdx.x, tid = threadIdx.x;
  const int mat = tb >> 4, tt = tb & 15;
  const int ib = (tt >> 2) * 64, ob = (tt & 3) * 64;
  const float* W = (mat == 0) ? Wq : (mat == 1) ? Wk : Wv;
  #pragma unroll
  for (int p = 0; p < 4; ++p) {
    int idx = p * 256 + tid;
    int r = idx >> 4, c4 = idx & 15;
    float4 f = *(const float4*)&W[(size_t)(ib + r) * 256 + ob + c4 * 4];
    t[r][c4 * 4 + 0] = f.x; t[r][c4 * 4 + 1] = f.y;
    t[r][c4 * 4 + 2] = f.z; t[r][c4 * 4 + 3] = f.w;
  }
  __syncthreads();
  #pragma unroll
  for (int p = 0; p < 4; ++p) {
    int idx = p * 256 + tid;
    int o = idx >> 4, i4 = idx & 15;
    ushort4 u;
    u.x = bf16_rn(t[i4 * 4 + 0][o]);
    u.y = bf16_rn(t[i4 * 4 + 1][o]);
    u.z = bf16_rn(t[i4 * 4 + 2][o]);
    u.w = bf16_rn(t[i4 * 4 + 3][o]);
    *(ushort4*)&wt[((size_t)mat * 256 + ob + o) * 256 + ib + i4 * 4] = u;
  }
}

// ---------------- K1: fused QKV projection GEMM ----------------
// A read from x (f32) and converted in-reg (xcast kernel eliminated).
// W tiles (64 cols x 256 K = 32 KB) double-buffered in LDS.
__global__ __launch_bounds__(256, 2) void qkv_kernel(
    const float* __restrict__ x, const uint16_t* __restrict__ wt,
    const float* __restrict__ bq, const float* __restrict__ bk, const float* __restrict__ bv,
    uint16_t* __restrict__ qo, uint16_t* __restrict__ ko, uint16_t* __restrict__ vo) {
  __shared__ char wsm[2][32768];
  const int tid = threadIdx.x;
  const int lane = tid & 63, wave = tid >> 6, quad = lane >> 4, lr = lane & 15;
  const int m0 = (blockIdx.x >> 2) * 256;
  const int cchunk = blockIdx.x & 3;          // 4 chunks of 192 cols over [q|k|v]
  stage_tile<64>(wt + (size_t)(cchunk * 192) * 256, wsm[0], tid);
  const float* ab = x + (size_t)(m0 + wave * 64) * EE;
  bf16x8 a[4][8];
  #pragma unroll
  for (int ms = 0; ms < 4; ++ms)
    #pragma unroll
    for (int f = 0; f < 8; ++f) {
      const float* rp = ab + (size_t)(ms * 16 + lr) * EE + f * 32 + quad * 8;
      a[ms][f] = pack_bf8(*(const float4*)rp, *(const float4*)(rp + 4));
    }
  for (int nc = 0; nc < 3; ++nc) {
    __syncthreads();
    if (nc < 2)
      stage_tile<64>(wt + (size_t)(cchunk * 192 + (nc + 1) * 64) * 256, wsm[(nc + 1) & 1], tid);
    const char* tile = wsm[nc & 1];
    #pragma unroll
    for (int nt = 0; nt < 4; ++nt) {
      const int eg0 = cchunk * 192 + nc * 64 + nt * 16;
      const int mat = eg0 >> 8;
      const int e = (eg0 & 255) + lr;
      const float* bias = (mat == 0) ? bq : (mat == 1) ? bk : bv;
      uint16_t* outp = (mat == 0) ? qo : (mat == 1) ? ko : vo;
      bf16x8 bf[8];
      #pragma unroll
      for (int f = 0; f < 8; ++f) bf[f] = read_frag(tile, nt * 16 + lr, f * 4 + quad);
      f32x4 acc[4] = {};
      #pragma unroll
      for (int f = 0; f < 8; ++f)
        #pragma unroll
        for (int ms = 0; ms < 4; ++ms)
          acc[ms] = mfma16(a[ms][f], bf[f], acc[ms]);
      const float bsv = bias[e];
      #pragma unroll
      for (int ms = 0; ms < 4; ++ms)
        #pragma unroll
        for (int r = 0; r < 4; ++r) {
          int row = m0 + wave * 64 + ms * 16 + quad * 4 + r;
          outp[(size_t)row * EE + e] = bf16_rn(acc[ms][r] + bsv);
        }
    }
  }
}

// ---------------- K2: pass A  l[s] = sum_t exp(q_s.k_t/16) ----------------
// A (64 q-rows/wave) resident in regs; K streamed through 64-key (32 KB)
// double-buffered LDS tiles via register-free global_load_lds. 8 iters.
__global__ __launch_bounds__(256, 2) void scores_l_kernel(
    const uint16_t* __restrict__ q, const uint16_t* __restrict__ k,
    float* __restrict__ lacc) {
  __shared__ char kt[2][32768];
  const int tid = threadIdx.x;
  const int lane = tid & 63, wave = tid >> 6, quad = lane >> 4, lr = lane & 15;
  const int idx = blockIdx.x;
  const int b = idx >> 7, rem = idx & 127, qblk = rem >> 3, kch = rem & 7;
  const uint16_t* qb = q + (size_t)(b * SS + qblk * 256 + wave * 64) * EE;
  const uint16_t* kb = k + (size_t)(b * SS + kch * 512) * EE;
  stage_tile<64>(kb, kt[0], tid);
  bf16x8 a[4][8];
  #pragma unroll
  for (int ms = 0; ms < 4; ++ms)
    #pragma unroll
    for (int f = 0; f < 8; ++f)
      a[ms][f] = *(const bf16x8*)(qb + (size_t)(ms * 16 + lr) * EE + f * 32 + quad * 8);
  float accl[16];
  #pragma unroll
  for (int i = 0; i < 16; ++i) accl[i] = 0.f;
  for (int it = 0; it < 8; ++it) {
    __syncthreads();                      // stage(it) landed; buf (it-1) free
    if (it + 1 < 8) stage_tile<64>(kb + (size_t)(it + 1) * 64 * EE, kt[(it + 1) & 1], tid);
    const char* tile = kt[it & 1];
    #pragma unroll
    for (int nt = 0; nt < 4; ++nt) {
      bf16x8 bf[8];
      #pragma unroll
      for (int f = 0; f < 8; ++f) bf[f] = read_frag(tile, nt * 16 + lr, f * 4 + quad);
      f32x4 acc[4] = {};
      #pragma unroll
      for (int f = 0; f < 8; ++f)
        #pragma unroll
        for (int ms = 0; ms < 4; ++ms)
          acc[ms] = mfma16(a[ms][f], bf[f], acc[ms]);
      #pragma unroll
      for (int ms = 0; ms < 4; ++ms)
        #pragma unroll
        for (int r = 0; r < 4; ++r)
          accl[ms * 4 + r] += EXP2(acc[ms][r] * C2);
    }
  }
  #pragma unroll
  for (int d = 1; d < 16; d <<= 1)
    #pragma unroll
    for (int i = 0; i < 16; ++i)
      accl[i] += __shfl_xor(accl[i], d, 64);
  if (lr == 0) {
    float* lp = lacc + b * SS + qblk * 256 + wave * 64;
    #pragma unroll
    for (int ms = 0; ms < 4; ++ms)
      #pragma unroll
      for (int r = 0; r < 4; ++r)
        atomicAdd(&lp[ms * 16 + quad * 4 + r], accl[ms * 4 + r]);
  }
}

// ---------------- K3: pass B  w[t] = sum_s exp(q_s.k_t/16) / l[s] ----------
__global__ __launch_bounds__(256, 2) void scores_w_kernel(
    const uint16_t* __restrict__ q, const uint16_t* __restrict__ k,
    const float* __restrict__ lacc, float* __restrict__ wacc) {
  __shared__ char qt[2][32768];
  const int tid = threadIdx.x;
  const int lane = tid & 63, wave = tid >> 6, quad = lane >> 4, lr = lane & 15;
  const int idx = blockIdx.x;
  const int b = idx >> 7, rem = idx & 127, kblk = rem >> 3, sch = rem & 7;
  const uint16_t* kb = k + (size_t)(b * SS + kblk * 256 + wave * 64) * EE;
  const uint16_t* qb = q + (size_t)(b * SS + sch * 512) * EE;
  const float* rlb = lacc + b * SS + sch * 512;
  stage_tile<64>(qb, qt[0], tid);
  bf16x8 a[4][8];
  #pragma unroll
  for (int ms = 0; ms < 4; ++ms)
    #pragma unroll
    for (int f = 0; f < 8; ++f)
      a[ms][f] = *(const bf16x8*)(kb + (size_t)(ms * 16 + lr) * EE + f * 32 + quad * 8);
  float accw[16];
  #pragma unroll
  for (int i = 0; i < 16; ++i) accw[i] = 0.f;
  for (int it = 0; it < 8; ++it) {
    __syncthreads();
    if (it + 1 < 8) stage_tile<64>(qb + (size_t)(it + 1) * 64 * EE, qt[(it + 1) & 1], tid);
    const char* tile = qt[it & 1];
    #pragma unroll
    for (int nt = 0; nt < 4; ++nt) {
      float rlv = RCP(rlb[it * 64 + nt * 16 + lr]);   // 1/l for col s
      bf16x8 bf[8];
      #pragma unroll
      for (int f = 0; f < 8; ++f) bf[f] = read_frag(tile, nt * 16 + lr, f * 4 + quad);
      f32x4 acc[4] = {};
      #pragma unroll
      for (int f = 0; f < 8; ++f)
        #pragma unroll
        for (int ms = 0; ms < 4; ++ms)
          acc[ms] = mfma16(a[ms][f], bf[f], acc[ms]);
      #pragma unroll
      for (int ms = 0; ms < 4; ++ms)
        #pragma unroll
        for (int r = 0; r < 4; ++r)
          accw[ms * 4 + r] += EXP2(acc[ms][r] * C2) * rlv;
    }
  }
  #pragma unroll
  for (int d = 1; d < 16; d <<= 1)
    #pragma unroll
    for (int i = 0; i < 16; ++i)
      accw[i] += __shfl_xor(accw[i], d, 64);
  if (lr == 0) {
    float* wp = wacc + b * SS + kblk * 256 + wave * 64;
    #pragma unroll
    for (int ms = 0; ms < 4; ++ms)
      #pragma unroll
      for (int r = 0; r < 4; ++r)
        atomicAdd(&wp[ms * 16 + quad * 4 + r], accw[ms * 4 + r]);
  }
}

// ---------------- K4: out[b,e] = (1/S) sum_t w[t] v[t,e] ----------------
// Deterministic (no atomics, writes every out element -> no out-memset).
__global__ void pool_kernel(const float* __restrict__ wsum, const uint16_t* __restrict__ v,
                            float* __restrict__ out) {
  __shared__ float red[16][16][4];
  const int b = blockIdx.x >> 2, ec = blockIdx.x & 3;   // 64-e chunk
  const int g = threadIdx.x & 15, tq = threadIdx.x >> 4;
  float acc[4] = {0.f, 0.f, 0.f, 0.f};
  const float* wp = wsum + b * SS;
  const uint16_t* vp = v + (size_t)(b * SS) * EE + ec * 64 + g * 4;
  for (int t = tq; t < SS; t += 16) {
    float wv = wp[t];
    ushort4 x4 = *(const ushort4*)(vp + (size_t)t * EE);
    acc[0] += wv * bf2f(x4.x);
    acc[1] += wv * bf2f(x4.y);
    acc[2] += wv * bf2f(x4.z);
    acc[3] += wv * bf2f(x4.w);
  }
  #pragma unroll
  for (int j = 0; j < 4; ++j) red[tq][g][j] = acc[j];
  __syncthreads();
  if (tq == 0) {
    float s[4] = {0.f, 0.f, 0.f, 0.f};
    #pragma unroll
    for (int t2 = 0; t2 < 16; ++t2)
      #pragma unroll
      for (int j = 0; j < 4; ++j) s[j] += red[t2][g][j];
    const float inv = 1.0f / 4096.0f;
    float4 o = {s[0] * inv, s[1] * inv, s[2] * inv, s[3] * inv};
    *(float4*)&out[b * 256 + ec * 64 + g * 4] = o;
  }
}

// ---------------- launch ----------------
extern "C" void kernel_launch(void* const* d_in, const int* in_sizes, int n_in,
                              void* d_out, int out_size, void* d_ws, size_t ws_size,
                              hipStream_t stream) {
  const float* x  = (const float*)d_in[0];
  const float* Wq = (const float*)d_in[1];
  const float* bq = (const float*)d_in[2];
  const float* Wk = (const float*)d_in[3];
  const float* bk = (const float*)d_in[4];
  const float* Wv = (const float*)d_in[5];
  const float* bv = (const float*)d_in[6];

  char* ws = (char*)d_ws;
  uint16_t* qb   = (uint16_t*)(ws);              //  8 MB  q bf16
  uint16_t* kb   = (uint16_t*)(ws + 8388608);    //  8 MB  k bf16
  uint16_t* vb   = (uint16_t*)(ws + 16777216);   //  8 MB  v bf16
  uint16_t* wt   = (uint16_t*)(ws + 25165824);   // 384 KB WT bf16 (q|k|v transposed)
  float* l_arr   = (float*)(ws + 25559040);      // 64 KB  row sums
  float* w_arr   = (float*)(ws + 25624576);      // 64 KB  col weights (adjacent)
  float* out     = (float*)d_out;

  hipMemsetAsync(l_arr, 0, 2 * 65536, stream);   // zeros l + w

  wcast_kernel<<<48, 256, 0, stream>>>(Wq, Wk, Wv, wt);
  qkv_kernel<<<256, 256, 0, stream>>>(x, wt, bq, bk, bv, qb, kb, vb);
  scores_l_kernel<<<512, 256, 0, stream>>>(qb, kb, l_arr);
  scores_w_kernel<<<512, 256, 0, stream>>>(qb, kb, l_arr, w_arr);
  pool_kernel<<<16, 256, 0, stream>>>(w_arr, vb, out);
}

// Round 4
// 177.404 us; speedup vs baseline: 1.5093x; 1.3748x over previous
//
#include <hip/hip_runtime.h>
#include <stdint.h>

#define SS 4096
#define EE 256
// log2(e)/16  (logit scale 1/NORM_FACTOR folded into exp2 conversion)
#define C2 0.0901684400555602f

typedef __bf16 bf16x8 __attribute__((ext_vector_type(8)));
typedef float  f32x4  __attribute__((ext_vector_type(4)));

#if __has_builtin(__builtin_amdgcn_exp2f)
#define EXP2(x) __builtin_amdgcn_exp2f(x)
#else
#define EXP2(x) exp2f(x)
#endif
#if __has_builtin(__builtin_amdgcn_rcpf)
#define RCP(x) __builtin_amdgcn_rcpf(x)
#else
#define RCP(x) (1.0f / (x))
#endif

__device__ __forceinline__ uint16_t bf16_rn(float f) {
  uint32_t u = __float_as_uint(f);
  uint32_t r = (u + 0x7fffu + ((u >> 16) & 1u)) >> 16;
  return (uint16_t)r;
}
__device__ __forceinline__ float bf2f(uint16_t h) {
  return __uint_as_float(((uint32_t)h) << 16);
}
__device__ __forceinline__ bf16x8 pack_bf8(float4 a, float4 b) {
  union { bf16x8 v; uint16_t u[8]; } r;
  r.u[0] = bf16_rn(a.x); r.u[1] = bf16_rn(a.y);
  r.u[2] = bf16_rn(a.z); r.u[3] = bf16_rn(a.w);
  r.u[4] = bf16_rn(b.x); r.u[5] = bf16_rn(b.y);
  r.u[6] = bf16_rn(b.z); r.u[7] = bf16_rn(b.w);
  return r.v;
}

__device__ __forceinline__ f32x4 mfma16(bf16x8 a, bf16x8 b, f32x4 c) {
  return __builtin_amdgcn_mfma_f32_16x16x32_bf16(a, b, c, 0, 0, 0);
}

// Stage R rows x 512B global -> LDS via global_load_lds(16B), XOR-swizzled
// (chunk cc of row r lands at physical cc^(r&7)); paired with read_frag.
// Register-free transport (R2 lesson: global->reg streaming starves VGPRs).
template<int R>
__device__ __forceinline__ void stage_tile(const uint16_t* gsrc, char* lds, int tid) {
  constexpr int NPER = (R * 32) / 256;
  const int wave = tid >> 6;
  #pragma unroll
  for (int c = 0; c < NPER; ++c) {
    int chunk = c * 256 + tid;
    int r = chunk >> 5;
    int ccl = (chunk & 31) ^ (r & 7);
    const char* gp = (const char*)gsrc + (r * 32 + ccl) * 16;
    char* lp = lds + (c * 256 + wave * 64) * 16;
    __builtin_amdgcn_global_load_lds(
        (const __attribute__((address_space(1))) uint32_t*)(uintptr_t)gp,
        (__attribute__((address_space(3))) uint32_t*)(uintptr_t)lp,
        16, 0, 0);
  }
}

__device__ __forceinline__ bf16x8 read_frag(const char* lds, int row, int cc) {
  int ccp = cc ^ (row & 7);
  return *(const bf16x8*)(lds + (row * 32 + ccp) * 16);
}

// ---------------- K0: W transpose-cast -> WT[out][in] bf16 ----------------
__global__ void wcast_kernel(const float* __restrict__ Wq, const float* __restrict__ Wk,
                             const float* __restrict__ Wv, uint16_t* __restrict__ wt) {
  __shared__ float t[64][65];
  const int tb = blockIdx.x, tid = threadIdx.x;
  const int mat = tb >> 4, tt = tb & 15;
  const int ib = (tt >> 2) * 64, ob = (tt & 3) * 64;
  const float* W = (mat == 0) ? Wq : (mat == 1) ? Wk : Wv;
  #pragma unroll
  for (int p = 0; p < 4; ++p) {
    int idx = p * 256 + tid;
    int r = idx >> 4, c4 = idx & 15;
    float4 f = *(const float4*)&W[(size_t)(ib + r) * 256 + ob + c4 * 4];
    t[r][c4 * 4 + 0] = f.x; t[r][c4 * 4 + 1] = f.y;
    t[r][c4 * 4 + 2] = f.z; t[r][c4 * 4 + 3] = f.w;
  }
  __syncthreads();
  #pragma unroll
  for (int p = 0; p < 4; ++p) {
    int idx = p * 256 + tid;
    int o = idx >> 4, i4 = idx & 15;
    ushort4 u;
    u.x = bf16_rn(t[i4 * 4 + 0][o]);
    u.y = bf16_rn(t[i4 * 4 + 1][o]);
    u.z = bf16_rn(t[i4 * 4 + 2][o]);
    u.w = bf16_rn(t[i4 * 4 + 3][o]);
    *(ushort4*)&wt[((size_t)mat * 256 + ob + o) * 256 + ib + i4 * 4] = u;
  }
}

// ---------------- K1: fused QKV projection GEMM ----------------
__global__ __launch_bounds__(256, 2) void qkv_kernel(
    const float* __restrict__ x, const uint16_t* __restrict__ wt,
    const float* __restrict__ bq, const float* __restrict__ bk, const float* __restrict__ bv,
    uint16_t* __restrict__ qo, uint16_t* __restrict__ ko, uint16_t* __restrict__ vo) {
  __shared__ char wsm[2][32768];
  const int tid = threadIdx.x;
  const int lane = tid & 63, wave = tid >> 6, quad = lane >> 4, lr = lane & 15;
  const int m0 = (blockIdx.x >> 2) * 256;
  const int cchunk = blockIdx.x & 3;          // 4 chunks of 192 cols over [q|k|v]
  stage_tile<64>(wt + (size_t)(cchunk * 192) * 256, wsm[0], tid);
  const float* ab = x + (size_t)(m0 + wave * 64) * EE;
  bf16x8 a[4][8];
  #pragma unroll
  for (int ms = 0; ms < 4; ++ms)
    #pragma unroll
    for (int f = 0; f < 8; ++f) {
      const float* rp = ab + (size_t)(ms * 16 + lr) * EE + f * 32 + quad * 8;
      a[ms][f] = pack_bf8(*(const float4*)rp, *(const float4*)(rp + 4));
    }
  for (int nc = 0; nc < 3; ++nc) {
    __syncthreads();
    if (nc < 2)
      stage_tile<64>(wt + (size_t)(cchunk * 192 + (nc + 1) * 64) * 256, wsm[(nc + 1) & 1], tid);
    const char* tile = wsm[nc & 1];
    #pragma unroll
    for (int nt = 0; nt < 4; ++nt) {
      const int eg0 = cchunk * 192 + nc * 64 + nt * 16;
      const int mat = eg0 >> 8;
      const int e = (eg0 & 255) + lr;
      const float* bias = (mat == 0) ? bq : (mat == 1) ? bk : bv;
      uint16_t* outp = (mat == 0) ? qo : (mat == 1) ? ko : vo;
      bf16x8 bf[8];
      #pragma unroll
      for (int f = 0; f < 8; ++f) bf[f] = read_frag(tile, nt * 16 + lr, f * 4 + quad);
      f32x4 acc[4] = {};
      #pragma unroll
      for (int f = 0; f < 8; ++f)
        #pragma unroll
        for (int ms = 0; ms < 4; ++ms)
          acc[ms] = mfma16(a[ms][f], bf[f], acc[ms]);
      const float bsv = bias[e];
      #pragma unroll
      for (int ms = 0; ms < 4; ++ms)
        #pragma unroll
        for (int r = 0; r < 4; ++r) {
          int row = m0 + wave * 64 + ms * 16 + quad * 4 + r;
          outp[(size_t)row * EE + e] = bf16_rn(acc[ms][r] + bsv);
        }
    }
  }
}

// ---------------- K2: pass A  l[s] = sum_t exp(q_s.k_t/16) ----------------
// A (64 q-rows/wave) resident in regs; K streamed through 64-key (32 KB)
// double-buffered LDS tiles via register-free global_load_lds. 8 iters.
__global__ __launch_bounds__(256, 2) void scores_l_kernel(
    const uint16_t* __restrict__ q, const uint16_t* __restrict__ k,
    float* __restrict__ lacc) {
  __shared__ char kt[2][32768];
  const int tid = threadIdx.x;
  const int lane = tid & 63, wave = tid >> 6, quad = lane >> 4, lr = lane & 15;
  const int idx = blockIdx.x;
  const int b = idx >> 7, rem = idx & 127, qblk = rem >> 3, kch = rem & 7;
  const uint16_t* qb = q + (size_t)(b * SS + qblk * 256 + wave * 64) * EE;
  const uint16_t* kb = k + (size_t)(b * SS + kch * 512) * EE;
  stage_tile<64>(kb, kt[0], tid);
  bf16x8 a[4][8];
  #pragma unroll
  for (int ms = 0; ms < 4; ++ms)
    #pragma unroll
    for (int f = 0; f < 8; ++f)
      a[ms][f] = *(const bf16x8*)(qb + (size_t)(ms * 16 + lr) * EE + f * 32 + quad * 8);
  float accl[16];
  #pragma unroll
  for (int i = 0; i < 16; ++i) accl[i] = 0.f;
  for (int it = 0; it < 8; ++it) {
    __syncthreads();                      // stage(it) landed; buf (it-1) free
    if (it + 1 < 8) stage_tile<64>(kb + (size_t)(it + 1) * 64 * EE, kt[(it + 1) & 1], tid);
    const char* tile = kt[it & 1];
    #pragma unroll
    for (int nt = 0; nt < 4; ++nt) {
      bf16x8 bf[8];
      #pragma unroll
      for (int f = 0; f < 8; ++f) bf[f] = read_frag(tile, nt * 16 + lr, f * 4 + quad);
      f32x4 acc[4] = {};
      #pragma unroll
      for (int f = 0; f < 8; ++f)
        #pragma unroll
        for (int ms = 0; ms < 4; ++ms)
          acc[ms] = mfma16(a[ms][f], bf[f], acc[ms]);
      #pragma unroll
      for (int ms = 0; ms < 4; ++ms)
        #pragma unroll
        for (int r = 0; r < 4; ++r)
          accl[ms * 4 + r] += EXP2(acc[ms][r] * C2);
    }
  }
  #pragma unroll
  for (int d = 1; d < 16; d <<= 1)
    #pragma unroll
    for (int i = 0; i < 16; ++i)
      accl[i] += __shfl_xor(accl[i], d, 64);
  if (lr == 0) {
    float* lp = lacc + b * SS + qblk * 256 + wave * 64;
    #pragma unroll
    for (int ms = 0; ms < 4; ++ms)
      #pragma unroll
      for (int r = 0; r < 4; ++r)
        atomicAdd(&lp[ms * 16 + quad * 4 + r], accl[ms * 4 + r]);
  }
}

// ---------------- K3: pass B  w[t] = sum_s exp(q_s.k_t/16) / l[s] ----------
__global__ __launch_bounds__(256, 2) void scores_w_kernel(
    const uint16_t* __restrict__ q, const uint16_t* __restrict__ k,
    const float* __restrict__ lacc, float* __restrict__ wacc) {
  __shared__ char qt[2][32768];
  const int tid = threadIdx.x;
  const int lane = tid & 63, wave = tid >> 6, quad = lane >> 4, lr = lane & 15;
  const int idx = blockIdx.x;
  const int b = idx >> 7, rem = idx & 127, kblk = rem >> 3, sch = rem & 7;
  const uint16_t* kb = k + (size_t)(b * SS + kblk * 256 + wave * 64) * EE;
  const uint16_t* qb = q + (size_t)(b * SS + sch * 512) * EE;
  const float* rlb = lacc + b * SS + sch * 512;
  stage_tile<64>(qb, qt[0], tid);
  bf16x8 a[4][8];
  #pragma unroll
  for (int ms = 0; ms < 4; ++ms)
    #pragma unroll
    for (int f = 0; f < 8; ++f)
      a[ms][f] = *(const bf16x8*)(kb + (size_t)(ms * 16 + lr) * EE + f * 32 + quad * 8);
  float accw[16];
  #pragma unroll
  for (int i = 0; i < 16; ++i) accw[i] = 0.f;
  for (int it = 0; it < 8; ++it) {
    __syncthreads();
    if (it + 1 < 8) stage_tile<64>(qb + (size_t)(it + 1) * 64 * EE, qt[(it + 1) & 1], tid);
    const char* tile = qt[it & 1];
    #pragma unroll
    for (int nt = 0; nt < 4; ++nt) {
      float rlv = RCP(rlb[it * 64 + nt * 16 + lr]);   // 1/l for col s
      bf16x8 bf[8];
      #pragma unroll
      for (int f = 0; f < 8; ++f) bf[f] = read_frag(tile, nt * 16 + lr, f * 4 + quad);
      f32x4 acc[4] = {};
      #pragma unroll
      for (int f = 0; f < 8; ++f)
        #pragma unroll
        for (int ms = 0; ms < 4; ++ms)
          acc[ms] = mfma16(a[ms][f], bf[f], acc[ms]);
      #pragma unroll
      for (int ms = 0; ms < 4; ++ms)
        #pragma unroll
        for (int r = 0; r < 4; ++r)
          accw[ms * 4 + r] += EXP2(acc[ms][r] * C2) * rlv;
    }
  }
  #pragma unroll
  for (int d = 1; d < 16; d <<= 1)
    #pragma unroll
    for (int i = 0; i < 16; ++i)
      accw[i] += __shfl_xor(accw[i], d, 64);
  if (lr == 0) {
    float* wp = wacc + b * SS + kblk * 256 + wave * 64;
    #pragma unroll
    for (int ms = 0; ms < 4; ++ms)
      #pragma unroll
      for (int r = 0; r < 4; ++r)
        atomicAdd(&wp[ms * 16 + quad * 4 + r], accw[ms * 4 + r]);
  }
}

// ---------------- K4a: pool stage 1 — per-64-row partial sums ----------------
// 256 blocks (1/CU): block (b, tc) sums 64 rows of w[t]*v[t,:] -> partial[b*64+tc][256].
// Coalesced: lanes cover 512 contiguous bytes of each v row.
__global__ void pool1_kernel(const float* __restrict__ wsum, const uint16_t* __restrict__ v,
                             float* __restrict__ partial) {
  __shared__ float red[4][256];
  const int b = blockIdx.x >> 6, tc = blockIdx.x & 63;
  const int tq = threadIdx.x >> 6, eg = threadIdx.x & 63;
  float acc[4] = {0.f, 0.f, 0.f, 0.f};
  const float* wp = wsum + b * SS + tc * 64;
  const uint16_t* vp = v + (size_t)(b * SS + tc * 64) * EE + eg * 4;
  #pragma unroll 4
  for (int t = tq; t < 64; t += 4) {
    float wv = wp[t];
    ushort4 x4 = *(const ushort4*)(vp + (size_t)t * EE);
    acc[0] += wv * bf2f(x4.x);
    acc[1] += wv * bf2f(x4.y);
    acc[2] += wv * bf2f(x4.z);
    acc[3] += wv * bf2f(x4.w);
  }
  #pragma unroll
  for (int j = 0; j < 4; ++j) red[tq][eg * 4 + j] = acc[j];
  __syncthreads();
  if (tq == 0) {
    float4 s;
    s.x = red[0][eg * 4 + 0] + red[1][eg * 4 + 0] + red[2][eg * 4 + 0] + red[3][eg * 4 + 0];
    s.y = red[0][eg * 4 + 1] + red[1][eg * 4 + 1] + red[2][eg * 4 + 1] + red[3][eg * 4 + 1];
    s.z = red[0][eg * 4 + 2] + red[1][eg * 4 + 2] + red[2][eg * 4 + 2] + red[3][eg * 4 + 2];
    s.w = red[0][eg * 4 + 3] + red[1][eg * 4 + 3] + red[2][eg * 4 + 3] + red[3][eg * 4 + 3];
    *(float4*)&partial[(size_t)blockIdx.x * 256 + eg * 4] = s;
  }
}

// ---------------- K4b: pool stage 2 — reduce 64 partials, write out ---------
__global__ void pool2_kernel(const float* __restrict__ partial, float* __restrict__ out) {
  const int b = blockIdx.x, e = threadIdx.x;
  float s = 0.f;
  #pragma unroll 8
  for (int c = 0; c < 64; ++c)
    s += partial[(size_t)(b * 64 + c) * 256 + e];
  out[b * 256 + e] = s * (1.0f / 4096.0f);
}

// ---------------- launch ----------------
extern "C" void kernel_launch(void* const* d_in, const int* in_sizes, int n_in,
                              void* d_out, int out_size, void* d_ws, size_t ws_size,
                              hipStream_t stream) {
  const float* x  = (const float*)d_in[0];
  const float* Wq = (const float*)d_in[1];
  const float* bq = (const float*)d_in[2];
  const float* Wk = (const float*)d_in[3];
  const float* bk = (const float*)d_in[4];
  const float* Wv = (const float*)d_in[5];
  const float* bv = (const float*)d_in[6];

  char* ws = (char*)d_ws;
  uint16_t* qb   = (uint16_t*)(ws);              //  8 MB  q bf16
  uint16_t* kb   = (uint16_t*)(ws + 8388608);    //  8 MB  k bf16
  uint16_t* vb   = (uint16_t*)(ws + 16777216);   //  8 MB  v bf16
  uint16_t* wt   = (uint16_t*)(ws + 25165824);   // 384 KB WT bf16 (q|k|v transposed)
  float* l_arr   = (float*)(ws + 25559040);      // 64 KB  row sums
  float* w_arr   = (float*)(ws + 25624576);      // 64 KB  col weights (adjacent)
  float* part    = (float*)(ws + 25690112);      // 256 KB pool partials
  float* out     = (float*)d_out;

  hipMemsetAsync(l_arr, 0, 2 * 65536, stream);   // zeros l + w

  wcast_kernel<<<48, 256, 0, stream>>>(Wq, Wk, Wv, wt);
  qkv_kernel<<<256, 256, 0, stream>>>(x, wt, bq, bk, bv, qb, kb, vb);
  scores_l_kernel<<<512, 256, 0, stream>>>(qb, kb, l_arr);
  scores_w_kernel<<<512, 256, 0, stream>>>(qb, kb, l_arr, w_arr);
  pool1_kernel<<<256, 256, 0, stream>>>(w_arr, vb, part);
  pool2_kernel<<<4, 256, 0, stream>>>(part, out);
}